// Round 16
// baseline (388.729 us; speedup 1.0000x reference)
//
#include <hip/hip_runtime.h>
#include <hip/hip_bf16.h>

typedef __attribute__((ext_vector_type(8))) short short8;
typedef __attribute__((ext_vector_type(4))) short short4v;
typedef __attribute__((ext_vector_type(4))) float f32x4;
typedef __attribute__((ext_vector_type(4))) float float4v;
typedef __attribute__((ext_vector_type(4))) int i32x4;

#define DEVFN static __device__ __forceinline__

// ---- problem constants ----
#define T_N   2048
#define S_N   512
#define L_N   1024
#define C_N   2048
#define H_N   16
#define HK_N  4
#define D_N   128
#define ST_N  2560   /* S+T  */
#define TOT_N 3584   /* L+S+T */
#define KV_N  512    /* HK*D  */

DEVFN short f2bf(float f) {
  union { float f; unsigned u; } v; v.f = f;
  return (short)((v.u + 0x7FFFu + ((v.u >> 16) & 1u)) >> 16);
}
DEVFN float bf2f(short s) {
  union { unsigned u; float f; } v; v.u = ((unsigned)(unsigned short)s) << 16;
  return v.f;
}
DEVFN void gload16(const void* g, void* l) {
  __builtin_amdgcn_global_load_lds(
      (__attribute__((address_space(1))) void*)(g),
      (__attribute__((address_space(3))) void*)(l), 16, 0, 0);
}

// ---------------- fused setup: 4 converts + RoPE tables ----------------
#define Q_A (S_N * C_N / 4)
#define Q_B (Q_A + T_N * C_N / 4)
#define Q_C (Q_B + L_N * KV_N / 4)
#define Q_D (Q_C + L_N * KV_N / 4)
#define TAB_E (Q_D + ST_N * 64)
__global__ void k_setup(const float* __restrict__ x, const float* __restrict__ stm,
                        const float* __restrict__ lk, const float* __restrict__ lv,
                        short* __restrict__ seq, short* __restrict__ Kf,
                        short* __restrict__ Vf, float* __restrict__ ct,
                        float* __restrict__ st_) {
  int i = blockIdx.x * 256 + threadIdx.x;
  if (i < Q_D) {
    const float* src; short* dst; int off;
    if (i < Q_A)      { src = stm; dst = seq;                         off = i; }
    else if (i < Q_B) { src = x;   dst = seq + (size_t)S_N * C_N;     off = i - Q_A; }
    else if (i < Q_C) { src = lk;  dst = Kf;                          off = i - Q_B; }
    else              { src = lv;  dst = Vf;                          off = i - Q_C; }
    float4v v = reinterpret_cast<const float4v*>(src)[off];
    short4v o;
    o[0] = f2bf(v[0]); o[1] = f2bf(v[1]); o[2] = f2bf(v[2]); o[3] = f2bf(v[3]);
    reinterpret_cast<short4v*>(dst)[off] = o;
  } else {
    int j = i - Q_D;
    int p = j >> 6, fq = j & 63;
    float freq = expf(-(float)fq * (logf(10000.0f) / 64.0f));
    float ang = (float)p * freq;
    ct[j] = cosf(ang);
    st_[j] = sinf(ang);
  }
}

// ------- fused transpose+convert of all 4 weights: [2048][cols] -> [cols][2048]
__global__ void k_tconv_all(const float* __restrict__ Wq, const float* __restrict__ Wk,
                            const float* __restrict__ Wv, const float* __restrict__ Wo,
                            short* __restrict__ WqT, short* __restrict__ WkT,
                            short* __restrict__ WvT, short* __restrict__ WoT) {
  __shared__ float tile[32][33];
  const int z = blockIdx.z;
  const float* in = (z == 0) ? Wq : (z == 1) ? Wk : (z == 2) ? Wv : Wo;
  short* outp     = (z == 0) ? WqT : (z == 1) ? WkT : (z == 2) ? WvT : WoT;
  const int cols = (z == 1 || z == 2) ? KV_N : C_N;
  if (blockIdx.x * 32 >= cols) return;
  int c0 = blockIdx.x * 32, r0 = blockIdx.y * 32;
  int tx = threadIdx.x, ty = threadIdx.y;   // (32,8)
#pragma unroll
  for (int i = 0; i < 4; i++)
    tile[ty + i * 8][tx] = in[(size_t)(r0 + ty + i * 8) * cols + c0 + tx];
  __syncthreads();
#pragma unroll
  for (int i = 0; i < 4; i++)
    outp[(size_t)(c0 + ty + i * 8) * C_N + r0 + tx] = f2bf(tile[tx][ty + i * 8]);
}

// ------- bf16 transpose of V_full head-slices: [3584][hk*128+d] -> Vt[hk][d][3584]
__global__ void k_tv(const short* __restrict__ vf, short* __restrict__ vt) {
  __shared__ short tile[32][33];
  int hk = blockIdx.z;
  int r0 = blockIdx.x * 32;   // key row
  int d0 = blockIdx.y * 32;   // d
  int tx = threadIdx.x, ty = threadIdx.y;
#pragma unroll
  for (int i = 0; i < 4; i++)
    tile[ty + i * 8][tx] = vf[(size_t)(r0 + ty + i * 8) * KV_N + hk * D_N + d0 + tx];
  __syncthreads();
  short* o = vt + (size_t)hk * D_N * TOT_N;
#pragma unroll
  for (int i = 0; i < 4; i++)
    o[(size_t)(d0 + ty + i * 8) * TOT_N + r0 + tx] = tile[tx][ty + i * 8];
}

// ---- 64x128-tile bf16 GEMM (2-phase dbuf, gload_lds + counted vmcnt) ----
// out-proj: C[2048][2048] f32 = ybuf[2048][2048] * WoT[2048][2048]^T
__global__ __launch_bounds__(256) void k_gemm_o(
    const short* __restrict__ A, const short* __restrict__ Bt,
    float* __restrict__ C) {
  __shared__ short lbuf[2 * 6144];   // 2 x 12KB (A 4KB + B 8KB)
  const int tid = threadIdx.x;
  const int w = tid >> 6, l = tid & 63;
  const int l15 = l & 15, lh = l >> 4;
  const int f0 = blockIdx.x;
  const int f = ((f0 & 7) << 6) + (f0 >> 3);        // bijective XCD swizzle, 512=8*64
  const int rb = (f >> 4) << 6, cb = (f & 15) << 7;
  const int wr = (w >> 1) << 5, wc = (w & 1) << 6;
  f32x4 acc[2][4] = {};
  const int cA = tid;                                // A chunks 0..255
  const short* pa = &A[(size_t)(rb + (cA >> 2)) * 2048 + (((cA ^ (cA >> 2)) & 3) << 3)];
  const int cB0 = tid, cB1 = 256 + tid;              // B chunks 0..511
  const short* pb0 = &Bt[(size_t)(cb + (cB0 >> 2)) * 2048 + (((cB0 ^ (cB0 >> 2)) & 3) << 3)];
  const short* pb1 = &Bt[(size_t)(cb + (cB1 >> 2)) * 2048 + (((cB1 ^ (cB1 >> 2)) & 3) << 3)];
  const int offA  = (w * 64) << 4;
  const int offB0 = 4096 + ((w * 64) << 4);
  const int offB1 = 4096 + ((256 + w * 64) << 4);
  char* lbase = (char*)lbuf;
  const int sw = (lh ^ (l15 & 3)) << 3;
  gload16(pa,  lbase + offA);
  gload16(pb0, lbase + offB0);
  gload16(pb1, lbase + offB1);
  int cur = 0;
  for (int kt = 0; kt < 2048; kt += 32) {
    const bool more = (kt + 32 < 2048);
    if (more) {
      char* p = lbase + (cur ^ 1) * 12288;
      gload16(pa  + kt + 32, p + offA);
      gload16(pb0 + kt + 32, p + offB0);
      gload16(pb1 + kt + 32, p + offB1);
      asm volatile("s_waitcnt vmcnt(3)" ::: "memory");
    } else {
      asm volatile("s_waitcnt vmcnt(0)" ::: "memory");
    }
    __builtin_amdgcn_s_barrier();
    __builtin_amdgcn_sched_barrier(0);
    const short* la = (const short*)(lbase + cur * 12288);
    const short* lb = (const short*)(lbase + cur * 12288 + 4096);
    short8 af[2], bg[4];
#pragma unroll
    for (int m = 0; m < 2; m++)
      af[m] = *reinterpret_cast<const short8*>(&la[(wr + m * 16 + l15) * 32 + sw]);
#pragma unroll
    for (int n = 0; n < 4; n++)
      bg[n] = *reinterpret_cast<const short8*>(&lb[(wc + n * 16 + l15) * 32 + sw]);
    __builtin_amdgcn_s_setprio(1);
#pragma unroll
    for (int m = 0; m < 2; m++)
#pragma unroll
      for (int n = 0; n < 4; n++)
        acc[m][n] = __builtin_amdgcn_mfma_f32_16x16x32_bf16(af[m], bg[n], acc[m][n], 0, 0, 0);
    __builtin_amdgcn_s_setprio(0);
    asm volatile("s_waitcnt lgkmcnt(0)" ::: "memory");
    __builtin_amdgcn_sched_barrier(0);
    __builtin_amdgcn_s_barrier();
    __builtin_amdgcn_sched_barrier(0);
    cur ^= 1;
  }
#pragma unroll
  for (int m = 0; m < 2; m++)
#pragma unroll
    for (int n = 0; n < 4; n++)
#pragma unroll
      for (int r = 0; r < 4; r++) {
        int row = rb + wr + m * 16 + lh * 4 + r;
        int col = cb + wc + n * 16 + l15;
        C[(size_t)row * 2048 + col] = acc[m][n][r];
      }
}

// merged QKV projection: 128x128 tile, 4 waves, 2-phase dbuf gload_lds +
// vmcnt(4); dead Q-row blocks skipped -> 416 blocks. Fused RoPE epilogue.
// A = seq [2560][2048], Bt = [WqT|WkT|WvT] [3072][2048]
__global__ __launch_bounds__(256) void k_gemm_qkv(
    const short* __restrict__ A, const short* __restrict__ Bt,
    short* __restrict__ qbuf, short* __restrict__ Kf, short* __restrict__ Vf,
    const float* __restrict__ ct, const float* __restrict__ st_) {
  const int Kd = C_N;
  __shared__ short lbuf[2 * 2 * 4096];   // [buf][A|B][4096 shorts] = 32 KB
  const int tid = threadIdx.x;
  const int w = tid >> 6, l = tid & 63;
  const int l15 = l & 15, lh = l >> 4;
  const int f0 = blockIdx.x;
  const int f = (f0 % 8) * 52 + f0 / 8;   // bijective XCD swizzle, 416 = 8*52
  int rb, cb;
  if (f < 256) {            // Q region: rows 512..2559 (16 M-tiles), cols 0..2047
    rb = 512 + ((f >> 4) << 7);
    cb = (f & 15) << 7;
  } else {                  // K/V region: rows 0..2559 (20 M-tiles), cols 2048..3071
    int g = f - 256;        // [0,160)
    rb = (g >> 3) << 7;
    cb = 2048 + ((g & 7) << 7);
  }
  const int wr = (w >> 1) << 6, wc = (w & 1) << 6;
  f32x4 acc[4][4] = {};
  const int c0 = tid, c1 = 256 + tid;
  const short* pa0 = &A[(size_t)(rb + (c0 >> 2)) * Kd + (((c0 ^ (c0 >> 2)) & 3) << 3)];
  const short* pa1 = &A[(size_t)(rb + (c1 >> 2)) * Kd + (((c1 ^ (c1 >> 2)) & 3) << 3)];
  const short* pb0 = &Bt[(size_t)(cb + (c0 >> 2)) * Kd + (((c0 ^ (c0 >> 2)) & 3) << 3)];
  const short* pb1 = &Bt[(size_t)(cb + (c1 >> 2)) * Kd + (((c1 ^ (c1 >> 2)) & 3) << 3)];
  const int offA0 = (w * 64) << 4, offA1 = ((256 + w * 64) << 4);
  char* lbase = (char*)lbuf;
  const int sw = (lh ^ (l15 & 3)) << 3;
  {
    gload16(pa0, lbase + offA0);
    gload16(pa1, lbase + offA1);
    gload16(pb0, lbase + 8192 + offA0);
    gload16(pb1, lbase + 8192 + offA1);
  }
  int cur = 0;
  for (int kt = 0; kt < Kd; kt += 32) {
    const bool more = (kt + 32 < Kd);
    if (more) {
      char* p = lbase + ((cur ^ 1) << 14);
      gload16(pa0 + kt + 32, p + offA0);
      gload16(pa1 + kt + 32, p + offA1);
      gload16(pb0 + kt + 32, p + 8192 + offA0);
      gload16(pb1 + kt + 32, p + 8192 + offA1);
      asm volatile("s_waitcnt vmcnt(4)" ::: "memory");
    } else {
      asm volatile("s_waitcnt vmcnt(0)" ::: "memory");
    }
    __builtin_amdgcn_s_barrier();
    __builtin_amdgcn_sched_barrier(0);
    const short* la = (const short*)(lbase + (cur << 14));
    const short* lb = (const short*)(lbase + (cur << 14) + 8192);
    short8 af[4], bg[4];
#pragma unroll
    for (int m = 0; m < 4; m++)
      af[m] = *reinterpret_cast<const short8*>(&la[(wr + m * 16 + l15) * 32 + sw]);
#pragma unroll
    for (int n = 0; n < 4; n++)
      bg[n] = *reinterpret_cast<const short8*>(&lb[(wc + n * 16 + l15) * 32 + sw]);
    __builtin_amdgcn_s_setprio(1);
#pragma unroll
    for (int m = 0; m < 4; m++)
#pragma unroll
      for (int n = 0; n < 4; n++)
        acc[m][n] = __builtin_amdgcn_mfma_f32_16x16x32_bf16(af[m], bg[n], acc[m][n], 0, 0, 0);
    __builtin_amdgcn_s_setprio(0);
    asm volatile("s_waitcnt lgkmcnt(0)" ::: "memory");
    __builtin_amdgcn_sched_barrier(0);
    __builtin_amdgcn_s_barrier();
    __builtin_amdgcn_sched_barrier(0);
    cur ^= 1;
  }
  // ---- epilogue with fused RoPE (pairs are adjacent lanes; shfl_xor(1)) ----
#pragma unroll
  for (int m = 0; m < 4; m++)
#pragma unroll
    for (int n = 0; n < 4; n++) {
      int coln = cb + wc + n * 16 + l15;
      const bool do_rope = coln < 2560;     // Q and K regions; V is not roped
      const int fidx = (coln & 127) >> 1;
#pragma unroll
      for (int r = 0; r < 4; r++) {
        int row = rb + wr + m * 16 + lh * 4 + r;
        float v = acc[m][n][r];
        float other = __shfl_xor(v, 1, 64);
        if (do_rope) {
          float co = ct[row * 64 + fidx];
          float si = st_[row * 64 + fidx];
          v = (l15 & 1) ? (other * si + v * co) : (v * co - other * si);
        }
        short bv = f2bf(v);
        if (coln < 2048) {
          if (row >= 512) qbuf[(size_t)(row - 512) * C_N + coln] = bv;
        } else if (coln < 2560) {
          Kf[(size_t)(L_N + row) * KV_N + (coln - 2048)] = bv;
        } else {
          Vf[(size_t)(L_N + row) * KV_N + (coln - 2560)] = bv;
        }
      }
    }
}

// ---------------- flash attention (swapped-QK, in-register P, split-K x4, ---
// 32 q-rows/wave; single-buffered K/V (32KB) reg staging (R13-verified body).
// 1024 blocks = 4/CU: p = f>>8 takes key-tile quarter [p*nkt/4,(p+1)*nkt/4).
// Raw-domain softmax (K2 inside, THR=90) exactly as R13.
// Partials: parts 0/1 -> pYa (ws overlay), parts 2/3 -> pYb (d_out scratch).
__global__ __launch_bounds__(256, 4) void k_attn(
    const short* __restrict__ Q,   // [2048][2048] roped (unscaled)
    const short* __restrict__ Kf,  // [3584][512]
    const short* __restrict__ Vt,  // [4][128][3584]
    short* __restrict__ pYa,       // [2][16][2048][128] bf16 partial y (p=0,1)
    short* __restrict__ pYb,       // [2][16][2048][128] bf16 partial y (p=2,3)
    float* __restrict__ pM,        // [4][16][2048] partial max
    float* __restrict__ pL) {      // [4][16][2048] partial denom
  __shared__ short kl[64 * 128];   // pi-row K tile (16 KB)
  __shared__ short vl[128 * 64];   // V^T tile [d][key] (16 KB)
  const int f = blockIdx.x;
  const int p = f >> 8;            // 0..3
  const int f8 = f & 255;
  const int hk = f8 & 3;
  const int qraw = (f8 >> 2) & 15;
  const int hh = (f8 >> 6) & 3;
  const int qb = (p & 1) ? (15 - qraw) : qraw;   // pairing: CU load = const
  const int h = hk * 4 + hh;
  const int tid = threadIdx.x, w = tid >> 6, l = tid & 63;
  const int l15 = l & 15, lh = l >> 4;
  const int qbase = qb << 7;
  const int qrow0 = qbase + (w << 5);      // 32 rows per wave
  short8 aqA[4], aqB[4];
#pragma unroll
  for (int kb = 0; kb < 4; kb++) {
    aqA[kb] = *reinterpret_cast<const short8*>(
        &Q[(size_t)(qrow0 + l15) * C_N + h * D_N + kb * 32 + lh * 8]);
    aqB[kb] = *reinterpret_cast<const short8*>(
        &Q[(size_t)(qrow0 + 16 + l15) * C_N + h * D_N + kb * 32 + lh * 8]);
  }
  short8 ones;
#pragma unroll
  for (int j = 0; j < 8; j++) ones[j] = (short)0x3F80;  // bf16 1.0
  f32x4 yA[8] = {}, yB[8] = {};
  f32x4 lA_ = {}, lB_ = {};
  float mA = -3.0e38f, mB = -3.0e38f;      // per-lane: qrow = qrow0 (+16) + l15
  const float K2 = 0.12751744f;            // (1/sqrt(128)) * log2(e)
  const float THR = 90.0f;                 // defer-max threshold (raw logits)
  const int nkt = ((qbase + 1663) >> 6) + 1;   // = 2*qb + 26
  const int tb = (p * nkt) >> 2;
  const int te = ((p + 1) * nkt) >> 2;     // each part >= 6 tiles; all rows live
  const short* psk[4];
  const short* psv[4];
  int ldsoff[4];
#pragma unroll
  for (int it = 0; it < 4; it++) {
    int c = it * 256 + tid;
    int kr = c >> 4, kkc = c & 15;                       // LDS row, chunk
    int pkr = (kr & 0x23) | ((kr & 0x0C) << 1) | ((kr >> 2) & 4);  // pi(row)
    psk[it] = &Kf[(size_t)pkr * KV_N + hk * D_N + ((kkc ^ (kr & 7)) << 3)];
    int vrow = c >> 3, vkc = c & 7;
    psv[it] = &Vt[(size_t)hk * D_N * TOT_N + (size_t)vrow * TOT_N + ((vkc ^ (vrow & 7)) << 3)];
    ldsoff[it] = (it * 256 + w * 64) << 4;
  }
  // prologue: stage tile tb directly (global_load_lds), full drain
#pragma unroll
  for (int it = 0; it < 4; it++)
    gload16(psk[it] + (size_t)tb * 64 * KV_N, (char*)kl + ldsoff[it]);
#pragma unroll
  for (int it = 0; it < 4; it++)
    gload16(psv[it] + (size_t)tb * 64, (char*)vl + ldsoff[it]);
  __syncthreads();
  for (int t = tb; t < te; t++) {
    const bool more = (t + 1 < te);
    // ---- issue tile t+1 loads into registers (latency hides under compute)
    short8 kreg[4], vreg[4];
    if (more) {
#pragma unroll
      for (int it = 0; it < 4; it++)
        kreg[it] = *reinterpret_cast<const short8*>(psk[it] + (size_t)(t + 1) * 64 * KV_N);
#pragma unroll
      for (int it = 0; it < 4; it++)
        vreg[it] = *reinterpret_cast<const short8*>(psv[it] + (size_t)(t + 1) * 64);
    }
    // ---- S^T = K Q^T for both q-halves; each bk read serves 2 MFMAs
    f32x4 sA[4] = {}, sB[4] = {};
    __builtin_amdgcn_s_setprio(1);
#pragma unroll
    for (int g = 0; g < 4; g++) {
      int row = g * 16 + l15;
#pragma unroll
      for (int kb = 0; kb < 4; kb++) {
        short8 bk = *reinterpret_cast<const short8*>(
            (const char*)kl + row * 256 + ((((kb << 2) + lh) ^ (row & 7)) << 4));
        sA[g] = __builtin_amdgcn_mfma_f32_16x16x32_bf16(bk, aqA[kb], sA[g], 0, 0, 0);
        sB[g] = __builtin_amdgcn_mfma_f32_16x16x32_bf16(bk, aqB[kb], sB[g], 0, 0, 0);
      }
    }
    __builtin_amdgcn_s_setprio(0);
    // ---- mask (boundary tiles only), per half
    if ((t * 64 + 63) > (1536 + qrow0)) {
      int qi = qrow0 + l15;
#pragma unroll
      for (int g = 0; g < 4; g++)
#pragma unroll
        for (int r = 0; r < 4; r++) {
          int key = t * 64 + ((g >> 1) << 5) + (lh << 3) + ((g & 1) << 2) + r;
          if (key > 1536 + qi) sA[g][r] = -3.0e38f;
        }
    }
    if ((t * 64 + 63) > (1536 + qrow0 + 16)) {
      int qi = qrow0 + 16 + l15;
#pragma unroll
      for (int g = 0; g < 4; g++)
#pragma unroll
        for (int r = 0; r < 4; r++) {
          int key = t * 64 + ((g >> 1) << 5) + (lh << 3) + ((g & 1) << 2) + r;
          if (key > 1536 + qi) sB[g][r] = -3.0e38f;
        }
    }
    // ---- defer-max online softmax, half A
    {
      float lm = sA[0][0];
#pragma unroll
      for (int g = 0; g < 4; g++)
#pragma unroll
        for (int r = 0; r < 4; r++) lm = fmaxf(lm, sA[g][r]);
      if (!__all(lm <= mA + THR)) {
        float rm = fmaxf(lm, __shfl_xor(lm, 16, 64));
        rm = fmaxf(rm, __shfl_xor(rm, 32, 64));
        float mn = fmaxf(mA, rm);
        float scf = __builtin_amdgcn_exp2f((mA - mn) * K2);
        mA = mn;
#pragma unroll
        for (int r = 0; r < 4; r++) {
          float sc_c = __shfl(scf, lh * 4 + r, 64);
          lA_[r] *= sc_c;
#pragma unroll
          for (int dg = 0; dg < 8; dg++) yA[dg][r] *= sc_c;
        }
      }
    }
    // ---- defer-max online softmax, half B
    {
      float lm = sB[0][0];
#pragma unroll
      for (int g = 0; g < 4; g++)
#pragma unroll
        for (int r = 0; r < 4; r++) lm = fmaxf(lm, sB[g][r]);
      if (!__all(lm <= mB + THR)) {
        float rm = fmaxf(lm, __shfl_xor(lm, 16, 64));
        rm = fmaxf(rm, __shfl_xor(rm, 32, 64));
        float mn = fmaxf(mB, rm);
        float scf = __builtin_amdgcn_exp2f((mB - mn) * K2);
        mB = mn;
#pragma unroll
        for (int r = 0; r < 4; r++) {
          float sc_c = __shfl(scf, lh * 4 + r, 64);
          lB_[r] *= sc_c;
#pragma unroll
          for (int dg = 0; dg < 8; dg++) yB[dg][r] *= sc_c;
        }
      }
    }
    // ---- P = exp2(s*K2 - m*K2); pack via v_cvt_pk_bf16_f32 into A-fragments
    union { i32x4 wv; short8 sv; } uA0, uA1, uB0, uB1;
    {
      const float mk = mA * K2;
      float pvv[16];
#pragma unroll
      for (int g = 0; g < 4; g++)
#pragma unroll
        for (int r = 0; r < 4; r++)
          pvv[g * 4 + r] = __builtin_amdgcn_exp2f(sA[g][r] * K2 - mk);
#pragma unroll
      for (int j = 0; j < 4; j++) {
        unsigned w0, w1;
        int b0 = (j >> 1) * 4 + 2 * (j & 1);
        int b1 = (2 + (j >> 1)) * 4 + 2 * (j & 1);
        asm("v_cvt_pk_bf16_f32 %0, %1, %2" : "=v"(w0) : "v"(pvv[b0]), "v"(pvv[b0 + 1]));
        asm("v_cvt_pk_bf16_f32 %0, %1, %2" : "=v"(w1) : "v"(pvv[b1]), "v"(pvv[b1 + 1]));
        uA0.wv[j] = (int)w0;
        uA1.wv[j] = (int)w1;
      }
    }
    {
      const float mk = mB * K2;
      float pvv[16];
#pragma unroll
      for (int g = 0; g < 4; g++)
#pragma unroll
        for (int r = 0; r < 4; r++)
          pvv[g * 4 + r] = __builtin_amdgcn_exp2f(sB[g][r] * K2 - mk);
#pragma unroll
      for (int j = 0; j < 4; j++) {
        unsigned w0, w1;
        int b0 = (j >> 1) * 4 + 2 * (j & 1);
        int b1 = (2 + (j >> 1)) * 4 + 2 * (j & 1);
        asm("v_cvt_pk_bf16_f32 %0, %1, %2" : "=v"(w0) : "v"(pvv[b0]), "v"(pvv[b0 + 1]));
        asm("v_cvt_pk_bf16_f32 %0, %1, %2" : "=v"(w1) : "v"(pvv[b1]), "v"(pvv[b1 + 1]));
        uB0.wv[j] = (int)w0;
        uB1.wv[j] = (int)w1;
      }
    }
    // ---- row sums via mfma(P, ones) -> C-layout
    lA_ = __builtin_amdgcn_mfma_f32_16x16x32_bf16(uA0.sv, ones, lA_, 0, 0, 0);
    lA_ = __builtin_amdgcn_mfma_f32_16x16x32_bf16(uA1.sv, ones, lA_, 0, 0, 0);
    lB_ = __builtin_amdgcn_mfma_f32_16x16x32_bf16(uB0.sv, ones, lB_, 0, 0, 0);
    lB_ = __builtin_amdgcn_mfma_f32_16x16x32_bf16(uB1.sv, ones, lB_, 0, 0, 0);
    // ---- PV: each bv read serves both halves (4 MFMAs per 2 reads)
    __builtin_amdgcn_s_setprio(1);
#pragma unroll
    for (int dg = 0; dg < 8; dg++) {
      int vrow = dg * 16 + l15;
      short8 bv0 = *reinterpret_cast<const short8*>(
          (const char*)vl + (vrow << 7) + ((lh ^ (vrow & 7)) << 4));
      short8 bv1 = *reinterpret_cast<const short8*>(
          (const char*)vl + (vrow << 7) + (((4 + lh) ^ (vrow & 7)) << 4));
      yA[dg] = __builtin_amdgcn_mfma_f32_16x16x32_bf16(uA0.sv, bv0, yA[dg], 0, 0, 0);
      yA[dg] = __builtin_amdgcn_mfma_f32_16x16x32_bf16(uA1.sv, bv1, yA[dg], 0, 0, 0);
      yB[dg] = __builtin_amdgcn_mfma_f32_16x16x32_bf16(uB0.sv, bv0, yB[dg], 0, 0, 0);
      yB[dg] = __builtin_amdgcn_mfma_f32_16x16x32_bf16(uB1.sv, bv1, yB[dg], 0, 0, 0);
    }
    __builtin_amdgcn_s_setprio(0);
    // ---- all waves done reading this tile's LDS
    asm volatile("s_waitcnt lgkmcnt(0)" ::: "memory");
    __builtin_amdgcn_sched_barrier(0);
    __builtin_amdgcn_s_barrier();
    __builtin_amdgcn_sched_barrier(0);
    // ---- write tile t+1 from registers (compiler inserts the vmcnt wait)
    if (more) {
#pragma unroll
      for (int it = 0; it < 4; it++)
        *reinterpret_cast<short8*>((char*)kl + ldsoff[it] + (l << 4)) = kreg[it];
#pragma unroll
      for (int it = 0; it < 4; it++)
        *reinterpret_cast<short8*>((char*)vl + ldsoff[it] + (l << 4)) = vreg[it];
    }
    __syncthreads();   // ds_writes visible to all waves
  }
  // ---- epilogue: partials (no division)
  short* py = (p < 2) ? (pYa + (size_t)p * 16 * 2048 * 128)
                      : (pYb + (size_t)(p - 2) * 16 * 2048 * 128);
  const size_t baseY = (size_t)h * 2048;
  const size_t baseML = (size_t)(p * 16 + h) * 2048;
#pragma unroll
  for (int dg = 0; dg < 8; dg++)
#pragma unroll
    for (int r = 0; r < 4; r++) {
      int rowA = qrow0 + lh * 4 + r;
      py[(baseY + rowA) * 128 + dg * 16 + l15] = f2bf(yA[dg][r]);
      py[(baseY + rowA + 16) * 128 + dg * 16 + l15] = f2bf(yB[dg][r]);
    }
  if (l15 == 0) {
#pragma unroll
    for (int r = 0; r < 4; r++) {
      pL[baseML + qrow0 + lh * 4 + r] = lA_[r];
      pL[baseML + qrow0 + 16 + lh * 4 + r] = lB_[r];
    }
  }
  if (lh == 0) {
    pM[baseML + qrow0 + l15] = mA;
    pM[baseML + qrow0 + 16 + l15] = mB;
  }
}

// ---------------- split-K merge: combine 4 partials (raw-domain) ------------
__global__ void k_merge(const short* __restrict__ pYa, const short* __restrict__ pYb,
                        const float* __restrict__ pM, const float* __restrict__ pL,
                        short* __restrict__ Y) {
  const int h = blockIdx.y;
  const int row = blockIdx.x * 16 + (threadIdx.x >> 4);
  const int d0 = (threadIdx.x & 15) * 8;
  const float K2 = 0.12751744f;
  float m[4], lv[4];
#pragma unroll
  for (int i = 0; i < 4; i++) {
    m[i]  = pM[(size_t)(i * 16 + h) * 2048 + row];
    lv[i] = pL[(size_t)(i * 16 + h) * 2048 + row];
  }
  float M = fmaxf(fmaxf(m[0], m[1]), fmaxf(m[2], m[3]));
  float a[4], den = 0.0f;
#pragma unroll
  for (int i = 0; i < 4; i++) {
    a[i] = __builtin_amdgcn_exp2f((m[i] - M) * K2);
    den += lv[i] * a[i];
  }
  float inv = 1.0f / den;
  float acc[8] = {};
#pragma unroll
  for (int i = 0; i < 4; i++) {
    const short* py = (i < 2) ? (pYa + (size_t)i * 16 * 2048 * 128)
                              : (pYb + (size_t)(i - 2) * 16 * 2048 * 128);
    short8 y = *reinterpret_cast<const short8*>(&py[((size_t)h * 2048 + row) * 128 + d0]);
#pragma unroll
    for (int j = 0; j < 8; j++) acc[j] += bf2f(y[j]) * a[i];
  }
  short8 o;
#pragma unroll
  for (int j = 0; j < 8; j++) o[j] = f2bf(acc[j] * inv);
  *reinterpret_cast<short8*>(&Y[(size_t)row * C_N + h * D_N + d0]) = o;
}

// ---------------- host launcher ----------------
extern "C" void kernel_launch(void* const* d_in, const int* in_sizes, int n_in,
                              void* d_out, int out_size, void* d_ws, size_t ws_size,
                              hipStream_t stream) {
  const float* x      = (const float*)d_in[0];
  const float* stm    = (const float*)d_in[1];
  // d_in[2] = long_q: unused (its query rows are discarded by y[:, -T:])
  const float* long_k = (const float*)d_in[3];
  const float* long_v = (const float*)d_in[4];
  const float* Wq     = (const float*)d_in[5];
  const float* Wk     = (const float*)d_in[6];
  const float* Wv     = (const float*)d_in[7];
  const float* Wo     = (const float*)d_in[8];
  float* out = (float*)d_out;

  // ---- workspace carve (bf16 stored as short) ----
  short* seq  = (short*)d_ws;                       // [2560][2048]
  short* WqT  = seq  + (size_t)ST_N * C_N;          // [2048][2048]  } contiguous:
  short* WkT  = WqT  + (size_t)C_N * C_N;           // [512][2048]   } Bt for merged
  short* WvT  = WkT  + (size_t)KV_N * C_N;          // [512][2048]   } QKV gemm
  short* WoT  = WvT  + (size_t)KV_N * C_N;          // [2048][2048]
  short* qbuf = WoT  + (size_t)C_N * C_N;           // [2048][2048]
  short* Kf   = qbuf + (size_t)T_N * C_N;           // [3584][512]
  short* Vf   = Kf   + (size_t)TOT_N * KV_N;        // [3584][512]
  short* Vt   = Vf   + (size_t)TOT_N * KV_N;        // [4][128][3584]
  short* ybuf = Vt   + (size_t)TOT_N * KV_N;        // [2048][2048]
  float* ctab = (float*)(ybuf + (size_t)T_N * C_N); // [2560][64]
  float* stab = ctab + (size_t)ST_N * 64;

  // split-K x4 partial buffers:
  //  parts 0/1 (16.78MB) + pM/pL (1.05MB) OVERLAY seq+WqT (18.87MB, dead
  //  once k_attn runs; rewritten by k_setup/k_tconv_all each launch).
  //  parts 2/3 (16.78MB) use d_out as scratch (fully rewritten by k_gemm_o).
  short* pYa = (short*)d_ws;                                 // [2][16][2048][128]
  float* pM  = (float*)(pYa + (size_t)2 * 16 * 2048 * 128);  // [4][16][2048]
  float* pL  = pM + (size_t)4 * 16 * 2048;                   // [4][16][2048]
  short* pYb = (short*)d_out;                                // [2][16][2048][128]

  // ---- fused converts + RoPE tables (1 launch) ----
  k_setup<<<TAB_E / 256, 256, 0, stream>>>(x, stm, long_k, long_v, seq, Kf, Vf, ctab, stab);

  // ---- fused weight transposes (1 launch) ----
  k_tconv_all<<<dim3(64, 64, 4), dim3(32, 8), 0, stream>>>(
      Wq, Wk, Wv, Wo, WqT, WkT, WvT, WoT);

  // ---- merged QKV projection + fused RoPE epilogue (416 blocks x 256 thr) ----
  k_gemm_qkv<<<416, 256, 0, stream>>>(seq, WqT, qbuf, Kf, Vf, ctab, stab);

  // ---- V transpose per kv-head ----
  k_tv<<<dim3(TOT_N / 32, D_N / 32, HK_N), dim3(32, 8), 0, stream>>>(Vf, Vt);

  // ---- attention (split-K x4, 32 q/wave, 1024 blocks = 4/CU) ----
  k_attn<<<1024, 256, 0, stream>>>(qbuf, Kf, Vt, pYa, pYb, pM, pL);

  // ---- merge partials -> ybuf ----
  k_merge<<<dim3(128, 16), 256, 0, stream>>>(pYa, pYb, pM, pL, ybuf);

  // ---- output projection (f32 out, 512 blocks) ----
  k_gemm_o<<<512, 256, 0, stream>>>(ybuf, WoT, out);
}

// Round 17
// 169.075 us; speedup vs baseline: 2.2992x; 2.2992x over previous
//
#include <hip/hip_runtime.h>
#include <hip/hip_bf16.h>

typedef __attribute__((ext_vector_type(8))) short short8;
typedef __attribute__((ext_vector_type(4))) short short4v;
typedef __attribute__((ext_vector_type(4))) float f32x4;
typedef __attribute__((ext_vector_type(4))) float float4v;
typedef __attribute__((ext_vector_type(4))) int i32x4;

#define DEVFN static __device__ __forceinline__

// ---- problem constants ----
#define T_N   2048
#define S_N   512
#define L_N   1024
#define C_N   2048
#define H_N   16
#define HK_N  4
#define D_N   128
#define ST_N  2560   /* S+T  */
#define TOT_N 3584   /* L+S+T */
#define KV_N  512    /* HK*D  */

DEVFN short f2bf(float f) {
  union { float f; unsigned u; } v; v.f = f;
  return (short)((v.u + 0x7FFFu + ((v.u >> 16) & 1u)) >> 16);
}
DEVFN float bf2f(short s) {
  union { unsigned u; float f; } v; v.u = ((unsigned)(unsigned short)s) << 16;
  return v.f;
}
DEVFN void gload16(const void* g, void* l) {
  __builtin_amdgcn_global_load_lds(
      (__attribute__((address_space(1))) void*)(g),
      (__attribute__((address_space(3))) void*)(l), 16, 0, 0);
}

// ---------------- fused setup: 4 converts + RoPE tables ----------------
#define Q_A (S_N * C_N / 4)
#define Q_B (Q_A + T_N * C_N / 4)
#define Q_C (Q_B + L_N * KV_N / 4)
#define Q_D (Q_C + L_N * KV_N / 4)
#define TAB_E (Q_D + ST_N * 64)
__global__ void k_setup(const float* __restrict__ x, const float* __restrict__ stm,
                        const float* __restrict__ lk, const float* __restrict__ lv,
                        short* __restrict__ seq, short* __restrict__ Kf,
                        short* __restrict__ Vf, float* __restrict__ ct,
                        float* __restrict__ st_) {
  int i = blockIdx.x * 256 + threadIdx.x;
  if (i < Q_D) {
    const float* src; short* dst; int off;
    if (i < Q_A)      { src = stm; dst = seq;                         off = i; }
    else if (i < Q_B) { src = x;   dst = seq + (size_t)S_N * C_N;     off = i - Q_A; }
    else if (i < Q_C) { src = lk;  dst = Kf;                          off = i - Q_B; }
    else              { src = lv;  dst = Vf;                          off = i - Q_C; }
    float4v v = reinterpret_cast<const float4v*>(src)[off];
    short4v o;
    o[0] = f2bf(v[0]); o[1] = f2bf(v[1]); o[2] = f2bf(v[2]); o[3] = f2bf(v[3]);
    reinterpret_cast<short4v*>(dst)[off] = o;
  } else {
    int j = i - Q_D;
    int p = j >> 6, fq = j & 63;
    float freq = expf(-(float)fq * (logf(10000.0f) / 64.0f));
    float ang = (float)p * freq;
    ct[j] = cosf(ang);
    st_[j] = sinf(ang);
  }
}

// ------- fused transpose+convert of all 4 weights: [2048][cols] -> [cols][2048]
__global__ void k_tconv_all(const float* __restrict__ Wq, const float* __restrict__ Wk,
                            const float* __restrict__ Wv, const float* __restrict__ Wo,
                            short* __restrict__ WqT, short* __restrict__ WkT,
                            short* __restrict__ WvT, short* __restrict__ WoT) {
  __shared__ float tile[32][33];
  const int z = blockIdx.z;
  const float* in = (z == 0) ? Wq : (z == 1) ? Wk : (z == 2) ? Wv : Wo;
  short* outp     = (z == 0) ? WqT : (z == 1) ? WkT : (z == 2) ? WvT : WoT;
  const int cols = (z == 1 || z == 2) ? KV_N : C_N;
  if (blockIdx.x * 32 >= cols) return;
  int c0 = blockIdx.x * 32, r0 = blockIdx.y * 32;
  int tx = threadIdx.x, ty = threadIdx.y;   // (32,8)
#pragma unroll
  for (int i = 0; i < 4; i++)
    tile[ty + i * 8][tx] = in[(size_t)(r0 + ty + i * 8) * cols + c0 + tx];
  __syncthreads();
#pragma unroll
  for (int i = 0; i < 4; i++)
    outp[(size_t)(c0 + ty + i * 8) * C_N + r0 + tx] = f2bf(tile[tx][ty + i * 8]);
}

// ------- bf16 transpose of V_full head-slices: [3584][hk*128+d] -> Vt[hk][d][3584]
__global__ void k_tv(const short* __restrict__ vf, short* __restrict__ vt) {
  __shared__ short tile[32][33];
  int hk = blockIdx.z;
  int r0 = blockIdx.x * 32;   // key row
  int d0 = blockIdx.y * 32;   // d
  int tx = threadIdx.x, ty = threadIdx.y;
#pragma unroll
  for (int i = 0; i < 4; i++)
    tile[ty + i * 8][tx] = vf[(size_t)(r0 + ty + i * 8) * KV_N + hk * D_N + d0 + tx];
  __syncthreads();
  short* o = vt + (size_t)hk * D_N * TOT_N;
#pragma unroll
  for (int i = 0; i < 4; i++)
    o[(size_t)(d0 + ty + i * 8) * TOT_N + r0 + tx] = tile[tx][ty + i * 8];
}

// ---- 64x128-tile bf16 GEMM (2-phase dbuf, gload_lds + counted vmcnt) ----
// out-proj: C[2048][2048] f32 = ybuf[2048][2048] * WoT[2048][2048]^T
__global__ __launch_bounds__(256) void k_gemm_o(
    const short* __restrict__ A, const short* __restrict__ Bt,
    float* __restrict__ C) {
  __shared__ short lbuf[2 * 6144];   // 2 x 12KB (A 4KB + B 8KB)
  const int tid = threadIdx.x;
  const int w = tid >> 6, l = tid & 63;
  const int l15 = l & 15, lh = l >> 4;
  const int f0 = blockIdx.x;
  const int f = ((f0 & 7) << 6) + (f0 >> 3);        // bijective XCD swizzle, 512=8*64
  const int rb = (f >> 4) << 6, cb = (f & 15) << 7;
  const int wr = (w >> 1) << 5, wc = (w & 1) << 6;
  f32x4 acc[2][4] = {};
  const int cA = tid;                                // A chunks 0..255
  const short* pa = &A[(size_t)(rb + (cA >> 2)) * 2048 + (((cA ^ (cA >> 2)) & 3) << 3)];
  const int cB0 = tid, cB1 = 256 + tid;              // B chunks 0..511
  const short* pb0 = &Bt[(size_t)(cb + (cB0 >> 2)) * 2048 + (((cB0 ^ (cB0 >> 2)) & 3) << 3)];
  const short* pb1 = &Bt[(size_t)(cb + (cB1 >> 2)) * 2048 + (((cB1 ^ (cB1 >> 2)) & 3) << 3)];
  const int offA  = (w * 64) << 4;
  const int offB0 = 4096 + ((w * 64) << 4);
  const int offB1 = 4096 + ((256 + w * 64) << 4);
  char* lbase = (char*)lbuf;
  const int sw = (lh ^ (l15 & 3)) << 3;
  gload16(pa,  lbase + offA);
  gload16(pb0, lbase + offB0);
  gload16(pb1, lbase + offB1);
  int cur = 0;
  for (int kt = 0; kt < 2048; kt += 32) {
    const bool more = (kt + 32 < 2048);
    if (more) {
      char* p = lbase + (cur ^ 1) * 12288;
      gload16(pa  + kt + 32, p + offA);
      gload16(pb0 + kt + 32, p + offB0);
      gload16(pb1 + kt + 32, p + offB1);
      asm volatile("s_waitcnt vmcnt(3)" ::: "memory");
    } else {
      asm volatile("s_waitcnt vmcnt(0)" ::: "memory");
    }
    __builtin_amdgcn_s_barrier();
    __builtin_amdgcn_sched_barrier(0);
    const short* la = (const short*)(lbase + cur * 12288);
    const short* lb = (const short*)(lbase + cur * 12288 + 4096);
    short8 af[2], bg[4];
#pragma unroll
    for (int m = 0; m < 2; m++)
      af[m] = *reinterpret_cast<const short8*>(&la[(wr + m * 16 + l15) * 32 + sw]);
#pragma unroll
    for (int n = 0; n < 4; n++)
      bg[n] = *reinterpret_cast<const short8*>(&lb[(wc + n * 16 + l15) * 32 + sw]);
    __builtin_amdgcn_s_setprio(1);
#pragma unroll
    for (int m = 0; m < 2; m++)
#pragma unroll
      for (int n = 0; n < 4; n++)
        acc[m][n] = __builtin_amdgcn_mfma_f32_16x16x32_bf16(af[m], bg[n], acc[m][n], 0, 0, 0);
    __builtin_amdgcn_s_setprio(0);
    asm volatile("s_waitcnt lgkmcnt(0)" ::: "memory");
    __builtin_amdgcn_sched_barrier(0);
    __builtin_amdgcn_s_barrier();
    __builtin_amdgcn_sched_barrier(0);
    cur ^= 1;
  }
#pragma unroll
  for (int m = 0; m < 2; m++)
#pragma unroll
    for (int n = 0; n < 4; n++)
#pragma unroll
      for (int r = 0; r < 4; r++) {
        int row = rb + wr + m * 16 + lh * 4 + r;
        int col = cb + wc + n * 16 + l15;
        C[(size_t)row * 2048 + col] = acc[m][n][r];
      }
}

// merged QKV projection: 128x128 tile, 4 waves, 2-phase dbuf gload_lds +
// vmcnt(4); dead Q-row blocks skipped -> 416 blocks. Fused RoPE epilogue.
// A = seq [2560][2048], Bt = [WqT|WkT|WvT] [3072][2048]
__global__ __launch_bounds__(256) void k_gemm_qkv(
    const short* __restrict__ A, const short* __restrict__ Bt,
    short* __restrict__ qbuf, short* __restrict__ Kf, short* __restrict__ Vf,
    const float* __restrict__ ct, const float* __restrict__ st_) {
  const int Kd = C_N;
  __shared__ short lbuf[2 * 2 * 4096];   // [buf][A|B][4096 shorts] = 32 KB
  const int tid = threadIdx.x;
  const int w = tid >> 6, l = tid & 63;
  const int l15 = l & 15, lh = l >> 4;
  const int f0 = blockIdx.x;
  const int f = (f0 % 8) * 52 + f0 / 8;   // bijective XCD swizzle, 416 = 8*52
  int rb, cb;
  if (f < 256) {            // Q region: rows 512..2559 (16 M-tiles), cols 0..2047
    rb = 512 + ((f >> 4) << 7);
    cb = (f & 15) << 7;
  } else {                  // K/V region: rows 0..2559 (20 M-tiles), cols 2048..3071
    int g = f - 256;        // [0,160)
    rb = (g >> 3) << 7;
    cb = 2048 + ((g & 7) << 7);
  }
  const int wr = (w >> 1) << 6, wc = (w & 1) << 6;
  f32x4 acc[4][4] = {};
  const int c0 = tid, c1 = 256 + tid;
  const short* pa0 = &A[(size_t)(rb + (c0 >> 2)) * Kd + (((c0 ^ (c0 >> 2)) & 3) << 3)];
  const short* pa1 = &A[(size_t)(rb + (c1 >> 2)) * Kd + (((c1 ^ (c1 >> 2)) & 3) << 3)];
  const short* pb0 = &Bt[(size_t)(cb + (c0 >> 2)) * Kd + (((c0 ^ (c0 >> 2)) & 3) << 3)];
  const short* pb1 = &Bt[(size_t)(cb + (c1 >> 2)) * Kd + (((c1 ^ (c1 >> 2)) & 3) << 3)];
  const int offA0 = (w * 64) << 4, offA1 = ((256 + w * 64) << 4);
  char* lbase = (char*)lbuf;
  const int sw = (lh ^ (l15 & 3)) << 3;
  {
    gload16(pa0, lbase + offA0);
    gload16(pa1, lbase + offA1);
    gload16(pb0, lbase + 8192 + offA0);
    gload16(pb1, lbase + 8192 + offA1);
  }
  int cur = 0;
  for (int kt = 0; kt < Kd; kt += 32) {
    const bool more = (kt + 32 < Kd);
    if (more) {
      char* p = lbase + ((cur ^ 1) << 14);
      gload16(pa0 + kt + 32, p + offA0);
      gload16(pa1 + kt + 32, p + offA1);
      gload16(pb0 + kt + 32, p + 8192 + offA0);
      gload16(pb1 + kt + 32, p + 8192 + offA1);
      asm volatile("s_waitcnt vmcnt(4)" ::: "memory");
    } else {
      asm volatile("s_waitcnt vmcnt(0)" ::: "memory");
    }
    __builtin_amdgcn_s_barrier();
    __builtin_amdgcn_sched_barrier(0);
    const short* la = (const short*)(lbase + (cur << 14));
    const short* lb = (const short*)(lbase + (cur << 14) + 8192);
    short8 af[4], bg[4];
#pragma unroll
    for (int m = 0; m < 4; m++)
      af[m] = *reinterpret_cast<const short8*>(&la[(wr + m * 16 + l15) * 32 + sw]);
#pragma unroll
    for (int n = 0; n < 4; n++)
      bg[n] = *reinterpret_cast<const short8*>(&lb[(wc + n * 16 + l15) * 32 + sw]);
    __builtin_amdgcn_s_setprio(1);
#pragma unroll
    for (int m = 0; m < 4; m++)
#pragma unroll
      for (int n = 0; n < 4; n++)
        acc[m][n] = __builtin_amdgcn_mfma_f32_16x16x32_bf16(af[m], bg[n], acc[m][n], 0, 0, 0);
    __builtin_amdgcn_s_setprio(0);
    asm volatile("s_waitcnt lgkmcnt(0)" ::: "memory");
    __builtin_amdgcn_sched_barrier(0);
    __builtin_amdgcn_s_barrier();
    __builtin_amdgcn_sched_barrier(0);
    cur ^= 1;
  }
  // ---- epilogue with fused RoPE (pairs are adjacent lanes; shfl_xor(1)) ----
#pragma unroll
  for (int m = 0; m < 4; m++)
#pragma unroll
    for (int n = 0; n < 4; n++) {
      int coln = cb + wc + n * 16 + l15;
      const bool do_rope = coln < 2560;     // Q and K regions; V is not roped
      const int fidx = (coln & 127) >> 1;
#pragma unroll
      for (int r = 0; r < 4; r++) {
        int row = rb + wr + m * 16 + lh * 4 + r;
        float v = acc[m][n][r];
        float other = __shfl_xor(v, 1, 64);
        if (do_rope) {
          float co = ct[row * 64 + fidx];
          float si = st_[row * 64 + fidx];
          v = (l15 & 1) ? (other * si + v * co) : (v * co - other * si);
        }
        short bv = f2bf(v);
        if (coln < 2048) {
          if (row >= 512) qbuf[(size_t)(row - 512) * C_N + coln] = bv;
        } else if (coln < 2560) {
          Kf[(size_t)(L_N + row) * KV_N + (coln - 2048)] = bv;
        } else {
          Vf[(size_t)(L_N + row) * KV_N + (coln - 2560)] = bv;
        }
      }
    }
}

// ---------------- flash attention (swapped-QK, in-register P, split-K x2, ---
// ---------------- 32 q-rows per wave: K/V LDS reads amortized over 2 halves)
// 512 blocks: p = f>>8, 16 qblocks x 16 heads; 4 waves x 32 q = 128 q/block.
// Single-buffered K (16KB) + V (16KB), register staging (R9/R13-verified).
__global__ __launch_bounds__(256, 2) void k_attn(
    const short* __restrict__ Q,   // [2048][2048] roped (unscaled)
    const short* __restrict__ Kf,  // [3584][512]
    const short* __restrict__ Vt,  // [4][128][3584]
    short* __restrict__ pY,        // [2][16][2048][128] bf16 partial y
    float* __restrict__ pM,        // [2][16][2048] partial max
    float* __restrict__ pL) {      // [2][16][2048] partial denom
  __shared__ short kl[64 * 128];   // pi-row K tile (16 KB)
  __shared__ short vl[128 * 64];   // V^T tile [d][key] (16 KB)
  const int f = blockIdx.x;
  const int p = f >> 8;
  const int f8 = f & 255;
  const int hk = f8 & 3;
  const int qraw = (f8 >> 2) & 15;
  const int hh = (f8 >> 6) & 3;
  const int qb = p ? (15 - qraw) : qraw;   // pairing: CU load = const 41 tiles
  const int h = hk * 4 + hh;
  const int tid = threadIdx.x, w = tid >> 6, l = tid & 63;
  const int l15 = l & 15, lh = l >> 4;
  const int qbase = qb << 7;
  const int qrow0 = qbase + (w << 5);      // 32 rows per wave
  short8 aqA[4], aqB[4];
#pragma unroll
  for (int kb = 0; kb < 4; kb++) {
    aqA[kb] = *reinterpret_cast<const short8*>(
        &Q[(size_t)(qrow0 + l15) * C_N + h * D_N + kb * 32 + lh * 8]);
    aqB[kb] = *reinterpret_cast<const short8*>(
        &Q[(size_t)(qrow0 + 16 + l15) * C_N + h * D_N + kb * 32 + lh * 8]);
  }
  short8 ones;
#pragma unroll
  for (int j = 0; j < 8; j++) ones[j] = (short)0x3F80;  // bf16 1.0
  f32x4 yA[8] = {}, yB[8] = {};
  f32x4 lA_ = {}, lB_ = {};
  float mA = -3.0e38f, mB = -3.0e38f;      // per-lane: qrow = qrow0 (+16) + l15
  const float K2 = 0.12751744f;            // (1/sqrt(128)) * log2(e)
  const float THR = 90.0f;                 // defer-max threshold (raw logits)
  const int nkt = ((qbase + 1663) >> 6) + 1;   // = 2*qb + 26
  const int th = nkt >> 1;
  const int t0 = p ? th : 0;
  const int t1 = p ? nkt : th;
  const short* psk[4];
  const short* psv[4];
  int ldsoff[4];
#pragma unroll
  for (int it = 0; it < 4; it++) {
    int c = it * 256 + tid;
    int kr = c >> 4, kkc = c & 15;                       // LDS row, chunk
    int pkr = (kr & 0x23) | ((kr & 0x0C) << 1) | ((kr >> 2) & 4);  // pi(row)
    psk[it] = &Kf[(size_t)pkr * KV_N + hk * D_N + ((kkc ^ (kr & 7)) << 3)];
    int vrow = c >> 3, vkc = c & 7;
    psv[it] = &Vt[(size_t)hk * D_N * TOT_N + (size_t)vrow * TOT_N + ((vkc ^ (vrow & 7)) << 3)];
    ldsoff[it] = (it * 256 + w * 64) << 4;
  }
  // prologue: stage tile t0 directly (global_load_lds), full drain
#pragma unroll
  for (int it = 0; it < 4; it++)
    gload16(psk[it] + (size_t)t0 * 64 * KV_N, (char*)kl + ldsoff[it]);
#pragma unroll
  for (int it = 0; it < 4; it++)
    gload16(psv[it] + (size_t)t0 * 64, (char*)vl + ldsoff[it]);
  __syncthreads();
  for (int t = t0; t < t1; t++) {
    const bool more = (t + 1 < t1);
    // ---- issue tile t+1 loads into registers (latency hides under compute)
    short8 kreg[4], vreg[4];
    if (more) {
#pragma unroll
      for (int it = 0; it < 4; it++)
        kreg[it] = *reinterpret_cast<const short8*>(psk[it] + (size_t)(t + 1) * 64 * KV_N);
#pragma unroll
      for (int it = 0; it < 4; it++)
        vreg[it] = *reinterpret_cast<const short8*>(psv[it] + (size_t)(t + 1) * 64);
    }
    // ---- S^T = K Q^T for both q-halves; each bk read serves 2 MFMAs
    f32x4 sA[4] = {}, sB[4] = {};
    __builtin_amdgcn_s_setprio(1);
#pragma unroll
    for (int g = 0; g < 4; g++) {
      int row = g * 16 + l15;
#pragma unroll
      for (int kb = 0; kb < 4; kb++) {
        short8 bk = *reinterpret_cast<const short8*>(
            (const char*)kl + row * 256 + ((((kb << 2) + lh) ^ (row & 7)) << 4));
        sA[g] = __builtin_amdgcn_mfma_f32_16x16x32_bf16(bk, aqA[kb], sA[g], 0, 0, 0);
        sB[g] = __builtin_amdgcn_mfma_f32_16x16x32_bf16(bk, aqB[kb], sB[g], 0, 0, 0);
      }
    }
    __builtin_amdgcn_s_setprio(0);
    // ---- mask (boundary tiles only), per half
    if ((t * 64 + 63) > (1536 + qrow0)) {
      int qi = qrow0 + l15;
#pragma unroll
      for (int g = 0; g < 4; g++)
#pragma unroll
        for (int r = 0; r < 4; r++) {
          int key = t * 64 + ((g >> 1) << 5) + (lh << 3) + ((g & 1) << 2) + r;
          if (key > 1536 + qi) sA[g][r] = -3.0e38f;
        }
    }
    if ((t * 64 + 63) > (1536 + qrow0 + 16)) {
      int qi = qrow0 + 16 + l15;
#pragma unroll
      for (int g = 0; g < 4; g++)
#pragma unroll
        for (int r = 0; r < 4; r++) {
          int key = t * 64 + ((g >> 1) << 5) + (lh << 3) + ((g & 1) << 2) + r;
          if (key > 1536 + qi) sB[g][r] = -3.0e38f;
        }
    }
    // ---- defer-max online softmax, half A
    {
      float lm = sA[0][0];
#pragma unroll
      for (int g = 0; g < 4; g++)
#pragma unroll
        for (int r = 0; r < 4; r++) lm = fmaxf(lm, sA[g][r]);
      if (!__all(lm <= mA + THR)) {
        float rm = fmaxf(lm, __shfl_xor(lm, 16, 64));
        rm = fmaxf(rm, __shfl_xor(rm, 32, 64));
        float mn = fmaxf(mA, rm);
        float scf = __builtin_amdgcn_exp2f((mA - mn) * K2);
        mA = mn;
#pragma unroll
        for (int r = 0; r < 4; r++) {
          float sc_c = __shfl(scf, lh * 4 + r, 64);
          lA_[r] *= sc_c;
#pragma unroll
          for (int dg = 0; dg < 8; dg++) yA[dg][r] *= sc_c;
        }
      }
    }
    // ---- defer-max online softmax, half B
    {
      float lm = sB[0][0];
#pragma unroll
      for (int g = 0; g < 4; g++)
#pragma unroll
        for (int r = 0; r < 4; r++) lm = fmaxf(lm, sB[g][r]);
      if (!__all(lm <= mB + THR)) {
        float rm = fmaxf(lm, __shfl_xor(lm, 16, 64));
        rm = fmaxf(rm, __shfl_xor(rm, 32, 64));
        float mn = fmaxf(mB, rm);
        float scf = __builtin_amdgcn_exp2f((mB - mn) * K2);
        mB = mn;
#pragma unroll
        for (int r = 0; r < 4; r++) {
          float sc_c = __shfl(scf, lh * 4 + r, 64);
          lB_[r] *= sc_c;
#pragma unroll
          for (int dg = 0; dg < 8; dg++) yB[dg][r] *= sc_c;
        }
      }
    }
    // ---- P = exp2(s*K2 - m*K2); pack via v_cvt_pk_bf16_f32 into A-fragments
    union { i32x4 wv; short8 sv; } uA0, uA1, uB0, uB1;
    {
      const float mk = mA * K2;
      float pvv[16];
#pragma unroll
      for (int g = 0; g < 4; g++)
#pragma unroll
        for (int r = 0; r < 4; r++)
          pvv[g * 4 + r] = __builtin_amdgcn_exp2f(sA[g][r] * K2 - mk);
#pragma unroll
      for (int j = 0; j < 4; j++) {
        unsigned w0, w1;
        int b0 = (j >> 1) * 4 + 2 * (j & 1);
        int b1 = (2 + (j >> 1)) * 4 + 2 * (j & 1);
        asm("v_cvt_pk_bf16_f32 %0, %1, %2" : "=v"(w0) : "v"(pvv[b0]), "v"(pvv[b0 + 1]));
        asm("v_cvt_pk_bf16_f32 %0, %1, %2" : "=v"(w1) : "v"(pvv[b1]), "v"(pvv[b1 + 1]));
        uA0.wv[j] = (int)w0;
        uA1.wv[j] = (int)w1;
      }
    }
    {
      const float mk = mB * K2;
      float pvv[16];
#pragma unroll
      for (int g = 0; g < 4; g++)
#pragma unroll
        for (int r = 0; r < 4; r++)
          pvv[g * 4 + r] = __builtin_amdgcn_exp2f(sB[g][r] * K2 - mk);
#pragma unroll
      for (int j = 0; j < 4; j++) {
        unsigned w0, w1;
        int b0 = (j >> 1) * 4 + 2 * (j & 1);
        int b1 = (2 + (j >> 1)) * 4 + 2 * (j & 1);
        asm("v_cvt_pk_bf16_f32 %0, %1, %2" : "=v"(w0) : "v"(pvv[b0]), "v"(pvv[b0 + 1]));
        asm("v_cvt_pk_bf16_f32 %0, %1, %2" : "=v"(w1) : "v"(pvv[b1]), "v"(pvv[b1 + 1]));
        uB0.wv[j] = (int)w0;
        uB1.wv[j] = (int)w1;
      }
    }
    // ---- row sums via mfma(P, ones) -> C-layout
    lA_ = __builtin_amdgcn_mfma_f32_16x16x32_bf16(uA0.sv, ones, lA_, 0, 0, 0);
    lA_ = __builtin_amdgcn_mfma_f32_16x16x32_bf16(uA1.sv, ones, lA_, 0, 0, 0);
    lB_ = __builtin_amdgcn_mfma_f32_16x16x32_bf16(uB0.sv, ones, lB_, 0, 0, 0);
    lB_ = __builtin_amdgcn_mfma_f32_16x16x32_bf16(uB1.sv, ones, lB_, 0, 0, 0);
    // ---- PV: each bv read serves both halves (4 MFMAs per 2 reads)
    __builtin_amdgcn_s_setprio(1);
#pragma unroll
    for (int dg = 0; dg < 8; dg++) {
      int vrow = dg * 16 + l15;
      short8 bv0 = *reinterpret_cast<const short8*>(
          (const char*)vl + (vrow << 7) + ((lh ^ (vrow & 7)) << 4));
      short8 bv1 = *reinterpret_cast<const short8*>(
          (const char*)vl + (vrow << 7) + (((4 + lh) ^ (vrow & 7)) << 4));
      yA[dg] = __builtin_amdgcn_mfma_f32_16x16x32_bf16(uA0.sv, bv0, yA[dg], 0, 0, 0);
      yA[dg] = __builtin_amdgcn_mfma_f32_16x16x32_bf16(uA1.sv, bv1, yA[dg], 0, 0, 0);
      yB[dg] = __builtin_amdgcn_mfma_f32_16x16x32_bf16(uB0.sv, bv0, yB[dg], 0, 0, 0);
      yB[dg] = __builtin_amdgcn_mfma_f32_16x16x32_bf16(uB1.sv, bv1, yB[dg], 0, 0, 0);
    }
    __builtin_amdgcn_s_setprio(0);
    // ---- all waves done reading this tile's LDS
    asm volatile("s_waitcnt lgkmcnt(0)" ::: "memory");
    __builtin_amdgcn_sched_barrier(0);
    __builtin_amdgcn_s_barrier();
    __builtin_amdgcn_sched_barrier(0);
    // ---- write tile t+1 from registers (compiler inserts the vmcnt wait)
    if (more) {
#pragma unroll
      for (int it = 0; it < 4; it++)
        *reinterpret_cast<short8*>((char*)kl + ldsoff[it] + (l << 4)) = kreg[it];
#pragma unroll
      for (int it = 0; it < 4; it++)
        *reinterpret_cast<short8*>((char*)vl + ldsoff[it] + (l << 4)) = vreg[it];
    }
    __syncthreads();   // ds_writes visible to all waves
  }
  // ---- epilogue: partials (no division)
  const size_t base = (size_t)(p * 16 + h) * 2048;
#pragma unroll
  for (int dg = 0; dg < 8; dg++)
#pragma unroll
    for (int r = 0; r < 4; r++) {
      int rowA = qrow0 + lh * 4 + r;
      pY[(base + rowA) * 128 + dg * 16 + l15] = f2bf(yA[dg][r]);
      pY[(base + rowA + 16) * 128 + dg * 16 + l15] = f2bf(yB[dg][r]);
    }
  if (l15 == 0) {
#pragma unroll
    for (int r = 0; r < 4; r++) {
      pL[base + qrow0 + lh * 4 + r] = lA_[r];
      pL[base + qrow0 + 16 + lh * 4 + r] = lB_[r];
    }
  }
  if (lh == 0) {
    pM[base + qrow0 + l15] = mA;
    pM[base + qrow0 + 16 + l15] = mB;
  }
}

// ---------------- split-K merge: combine 2 partials, write ybuf bf16 --------
__global__ void k_merge(const short* __restrict__ pY, const float* __restrict__ pM,
                        const float* __restrict__ pL, short* __restrict__ Y) {
  const int h = blockIdx.y;
  const int row = blockIdx.x * 16 + (threadIdx.x >> 4);
  const int d0 = (threadIdx.x & 15) * 8;
  const size_t b0 = (size_t)h * 2048 + row;
  const size_t b1 = (size_t)(16 + h) * 2048 + row;
  const float K2 = 0.12751744f;
  float m0 = pM[b0], m1 = pM[b1];
  float l0 = pL[b0], l1 = pL[b1];
  float M = fmaxf(m0, m1);
  float a0 = __builtin_amdgcn_exp2f((m0 - M) * K2);
  float a1 = __builtin_amdgcn_exp2f((m1 - M) * K2);
  float inv = 1.0f / (l0 * a0 + l1 * a1);
  short8 y0 = *reinterpret_cast<const short8*>(&pY[b0 * 128 + d0]);
  short8 y1 = *reinterpret_cast<const short8*>(&pY[b1 * 128 + d0]);
  short8 o;
#pragma unroll
  for (int j = 0; j < 8; j++)
    o[j] = f2bf((bf2f(y0[j]) * a0 + bf2f(y1[j]) * a1) * inv);
  *reinterpret_cast<short8*>(&Y[(size_t)row * C_N + h * D_N + d0]) = o;
}

// ---------------- host launcher ----------------
extern "C" void kernel_launch(void* const* d_in, const int* in_sizes, int n_in,
                              void* d_out, int out_size, void* d_ws, size_t ws_size,
                              hipStream_t stream) {
  const float* x      = (const float*)d_in[0];
  const float* stm    = (const float*)d_in[1];
  // d_in[2] = long_q: unused (its query rows are discarded by y[:, -T:])
  const float* long_k = (const float*)d_in[3];
  const float* long_v = (const float*)d_in[4];
  const float* Wq     = (const float*)d_in[5];
  const float* Wk     = (const float*)d_in[6];
  const float* Wv     = (const float*)d_in[7];
  const float* Wo     = (const float*)d_in[8];
  float* out = (float*)d_out;

  // ---- workspace carve (bf16 stored as short) ----
  short* seq  = (short*)d_ws;                       // [2560][2048]
  short* WqT  = seq  + (size_t)ST_N * C_N;          // [2048][2048]  } contiguous:
  short* WkT  = WqT  + (size_t)C_N * C_N;           // [512][2048]   } Bt for merged
  short* WvT  = WkT  + (size_t)KV_N * C_N;          // [512][2048]   } QKV gemm
  short* WoT  = WvT  + (size_t)KV_N * C_N;          // [2048][2048]
  short* qbuf = WoT  + (size_t)C_N * C_N;           // [2048][2048]
  short* Kf   = qbuf + (size_t)T_N * C_N;           // [3584][512]
  short* Vf   = Kf   + (size_t)TOT_N * KV_N;        // [3584][512]
  short* Vt   = Vf   + (size_t)TOT_N * KV_N;        // [4][128][3584]
  short* ybuf = Vt   + (size_t)TOT_N * KV_N;        // [2048][2048]
  float* ctab = (float*)(ybuf + (size_t)T_N * C_N); // [2560][64]
  float* stab = ctab + (size_t)ST_N * 64;

  // split-K partial buffers: OVERLAY on seq+WqT (both dead once k_attn runs;
  // rewritten by k_setup/k_tconv_all at the start of every launch).
  short* pY = (short*)d_ws;                          // [2][16][2048][128]
  float* pM = (float*)(pY + (size_t)2 * 16 * 2048 * 128);  // [2][16][2048]
  float* pL = pM + (size_t)2 * 16 * 2048;                  // [2][16][2048]

  // ---- fused converts + RoPE tables (1 launch) ----
  k_setup<<<TAB_E / 256, 256, 0, stream>>>(x, stm, long_k, long_v, seq, Kf, Vf, ctab, stab);

  // ---- fused weight transposes (1 launch) ----
  k_tconv_all<<<dim3(64, 64, 4), dim3(32, 8), 0, stream>>>(
      Wq, Wk, Wv, Wo, WqT, WkT, WvT, WoT);

  // ---- merged QKV projection + fused RoPE epilogue (416 blocks x 256 thr) ----
  k_gemm_qkv<<<416, 256, 0, stream>>>(seq, WqT, qbuf, Kf, Vf, ctab, stab);

  // ---- V transpose per kv-head ----
  k_tv<<<dim3(TOT_N / 32, D_N / 32, HK_N), dim3(32, 8), 0, stream>>>(Vf, Vt);

  // ---- attention (split-K x2, 32 q/wave, 512 blocks) ----
  k_attn<<<512, 256, 0, stream>>>(qbuf, Kf, Vt, pY, pM, pL);

  // ---- merge partials -> ybuf ----
  k_merge<<<dim3(128, 16), 256, 0, stream>>>(pY, pM, pL, ybuf);

  // ---- output projection (f32 out, 512 blocks) ----
  k_gemm_o<<<512, 256, 0, stream>>>(ybuf, WoT, out);
}